// Round 13
// baseline (164.077 us; speedup 1.0000x reference)
//
#include <hip/hip_runtime.h>
#include <cmath>

// ---------------------------------------------------------------------------
// Bit-exact replication of the reference's f32 cumsum TREE (JAX associative
// scan), validated rounds 5-12 (absmax 1.831e-3 all). Round 12 accounting:
// synth4 62 us (WRITE_SIZE 48 MB = 3M atomics x 16 B write-through), scan4
// ~40 us at only 6.25 waves/SIMD (vs ~9 us VALU floor), ~30 us dispatch
// overhead. This round: (1) k_scan4 at 1024 threads/block (16 waves -> 32
// resident waves/CU, better phase-1 packing; same tree, same association);
// (2) synth4 KZ 4->2 (half the staging, half the atomics; still ~23
// waves/CU). Chaotic-path dag unchanged.
// ---------------------------------------------------------------------------
#pragma clang fp contract(off)

#define SRF   48000.0f
#define NYQF  21600.0f                    // fp32(48000*0.45), exact
constexpr float  TWO_PI_F  = 6.283185307179586476925286766559f;  // 0x40C90FDB
constexpr double INV_2PI_D = 0.15915494309189533576888376337251;
constexpr float  RC1 = (float)INV_2PI_D;
constexpr float  RC2 = (float)(INV_2PI_D - (double)RC1);
constexpr double INV_SR_D = 1.0 / 48000.0;
constexpr float  DD1 = (float)INV_SR_D;
constexpr float  DD2 = (float)(INV_SR_D - (double)DD1);

__device__ __forceinline__ float hsin_rev(float r) {  // sin(2*pi*r)
#if __has_builtin(__builtin_amdgcn_sinf)
    return __builtin_amdgcn_sinf(r);                  // v_sin_f32: revolutions
#else
    return __sinf(r * TWO_PI_F);
#endif
}

// Correctly-rounded t/48000 via double-float mul (== IEEE f32 divide here;
// proved: no halfway cases, err 2^-47 << 2^-33.5 boundary distance).
__device__ __forceinline__ float div48000(float t) {
    float h = t * DD1;
    float r = __builtin_fmaf(t, DD1, -h);
    float s = __builtin_fmaf(t, DD2, r);
    return h + s;
}

// sin(ph) for f32 ph: double-float reduction to revolutions (|err|<=2^-25 rev)
__device__ __forceinline__ float sin_phase(float ph) {
    float h  = ph * RC1;
    float r  = __builtin_fmaf(ph, RC1, -h);
    float s  = __builtin_fmaf(ph, RC2, r);
    float nn = __builtin_rintf(h);
    float fr = (h - nn) + s;
    return hsin_rev(fr);
}

// group-of-4 broadcast: value of lane (lane&~3)+idx  (idx=0,1,2 static)
template <int IDX>
__device__ __forceinline__ float grp4_bcast(float v, int lb) {
#if __has_builtin(__builtin_amdgcn_ds_swizzle)
    constexpr int imm = (IDX << 5) | 0x1C;
    return __int_as_float(__builtin_amdgcn_ds_swizzle(__float_as_int(v), imm));
#else
    return __shfl(v, lb + IDX);
#endif
}

// kc[b,k] = fp32(k * fp32(sqrt(fp32(1 + fp32(inh*k^2)))))  -- np/jnp-exact
__device__ __forceinline__ float kcval(int k, float ib) {
    float kf = (float)(k + 1);
    float k2 = kf * kf;
    float m  = ib * k2;
    float s1 = 1.0f + m;
    float st = (float)sqrt((double)s1);
    return kf * st;
}

// ---- K1: f0_up[b,j] (np-exact fp32 interp) + zero-init of out --------------
__global__ void __launch_bounds__(256) k_f0up(const float* __restrict__ f0,
        float* __restrict__ f0up, float* __restrict__ out,
        int T, int n, float pf) {
    int j = blockIdx.x * 256 + threadIdx.x;
    int b = blockIdx.y;
    if (j >= n) return;
    float pos = ((float)j + 0.5f);
    pos = pos * pf;
    pos = pos - 0.5f;
    pos = fmaxf(pos, 0.0f);
    pos = fminf(pos, (float)(T - 1));
    int   i0 = (int)pos;
    int   i1 = min(i0 + 1, T - 1);
    float w  = pos - (float)i0;
    float omw = 1.0f - w;
    const float* fb = f0 + b * T;
    f0up[(size_t)b * n + j] = fb[i0] * omw + fb[i1] * w;
    out[(size_t)b * n + j]  = 0.0f;            // harness poisons out; we own it
}

// ---- K2a: per (b,k) produce scan4 (level-4 inclusive tree scan) ------------
// 1024 threads/block (16 waves) for packing; rows padded: sp[0]=0.
#define SCAN_TPB 1024
__global__ void __launch_bounds__(SCAN_TPB) k_scan4(const float* __restrict__ f0up,
        const float* __restrict__ inh, float* __restrict__ scan4,
        int N, int n) {
    __shared__ float lv[6016];
    const int k   = blockIdx.x;
    const int b   = blockIdx.y;
    const int tid = threadIdx.x;
    const float kc = kcval(k, inh[b]);
    const float4* f4 = (const float4*)(f0up + (size_t)b * n);
    const int len4 = n >> 4;

    auto l2of = [&](float4 v) -> float {
        float a0 = div48000(TWO_PI_F * (kc * v.x));
        float a1 = div48000(TWO_PI_F * (kc * v.y));
        float a2 = div48000(TWO_PI_F * (kc * v.z));
        float a3 = div48000(TWO_PI_F * (kc * v.w));
        return (a0 + a1) + (a2 + a3);
    };
    for (int i = tid; i < len4; i += SCAN_TPB) {
        float s01 = l2of(f4[4*i])     + l2of(f4[4*i + 1]);
        float s23 = l2of(f4[4*i + 2]) + l2of(f4[4*i + 3]);
        lv[i] = s01 + s23;                     // L4[i] = L3[2i]+L3[2i+1]
    }
    __syncthreads();

    // upsweep
    int offp = 0, lenp = len4, P = 4;
    for (int l = 5; ; ++l) {
        int lenc = lenp >> 1;
        int offc = offp + lenp;
        for (int i = tid; i < lenc; i += SCAN_TPB)
            lv[offc + i] = lv[offp + 2*i] + lv[offp + 2*i + 1];
        __syncthreads();
        P = l;
        if (lenc == 1) break;
        offp = offc; lenp = lenc;
    }
    // downsweep (round-5-validated formulas)
    for (int l = P - 1; l >= 4; --l) {
        int lenl = n >> l;
        int offl = 0;
        for (int m = 4; m < l; ++m) offl += (n >> m);
        int offh = offl + lenl;
        int lenh = n >> (l + 1);
        float*       arr = lv + offl;
        const float* hi  = lv + offh;
        for (int i = tid; i < lenh; i += SCAN_TPB) {
            float v = hi[i];
            int e = 2*i + 2;
            if (e < lenl) arr[e] = v + arr[e];
            arr[2*i + 1] = v;
        }
        __syncthreads();
    }
    float* sp = scan4 + (size_t)(b * N + k) * (len4 + 1);
    if (tid == 0) sp[0] = 0.0f;
    for (int i = tid; i < len4; i += SCAN_TPB) sp[1 + i] = lv[i];
}

// ---- K2b: 4 lanes per 16-j group; tree partials via group broadcasts -------
__global__ void __launch_bounds__(256) k_synth4(
        const float* __restrict__ harm, const float* __restrict__ f0up,
        const float* __restrict__ inh,  const float* __restrict__ scan4,
        float* __restrict__ out, int B, int T, int N, int n, float pf, int kpg) {
    const int tid  = threadIdx.x;
    const int b    = blockIdx.y;
    const int k0   = blockIdx.z * kpg;
    const int g    = blockIdx.x * 256 + tid;   // global lane id
    const int q    = g >> 2;                   // 16-sample group
    const int c    = g & 3;                    // quarter within group
    const int NG   = n >> 4;
    const int NGP  = NG + 1;                   // padded row length
    const int kend = min(k0 + kpg, N);
    const int kact = kend - k0;
    const bool valid = q < NG;

    __shared__ float2 amps[8 * 64];            // (a0, a1-a0) x k (span 1024 j)
    __shared__ float  kcs[64];

    const float ib    = inh[b];
    const float tmaxf = (float)(T - 1);
    for (int i = tid; i < kact; i += 256) kcs[i] = kcval(k0 + i, ib);

    const int j0blk = blockIdx.x * 1024;
    int i0min;
    {
        float p = ((float)j0blk + 0.5f);
        p = p * pf; p = p - 0.5f;
        p = fmaxf(p, 0.0f); p = fminf(p, tmaxf);
        i0min = (int)p;
    }
    for (int idx = tid; idx < 8 * kact; idx += 256) {
        int r = idx / kact, kk = idx - r * kact;
        int r0 = min(i0min + r, T - 1);
        int r1 = min(i0min + r + 1, T - 1);
        float a0 = harm[((size_t)b * T + r0) * N + (k0 + kk)];
        float a1 = harm[((size_t)b * T + r1) * N + (k0 + kk)];
        amps[idx] = make_float2(a0, a1 - a0);  // blend = fmaf(w, d, a0)
    }
    __syncthreads();                           // last barrier

    float u0=0.f,u1=0.f,u2=0.f,u3=0.f;
    float w0=0.f,w1=0.f,w2=0.f,w3=0.f;
    int   a0o=0,a1o=0,a2o=0,a3o=0;
    float um = __builtin_inff();
    if (valid) {
        const float4 v = *(const float4*)(f0up + (size_t)b * n + (size_t)q * 16 + c * 4);
        u0=v.x; u1=v.y; u2=v.z; u3=v.w;
        um = fminf(fminf(u0,u1), fminf(u2,u3));
        const int jb = q * 16 + c * 4;
        #pragma unroll
        for (int i = 0; i < 4; ++i) {
            float p = ((float)(jb + i) + 0.5f);
            p = p * pf; p = p - 0.5f;
            p = fmaxf(p, 0.0f); p = fminf(p, tmaxf);
            int i0 = (int)p;
            float wv = p - (float)i0;
            int aoo  = (i0 - i0min) * kact;
            if (i==0){w0=wv;a0o=aoo;}
            else if (i==1){w1=wv;a1o=aoo;}
            else if (i==2){w2=wv;a2o=aoo;}
            else {w3=wv;a3o=aoo;}
        }
    }
    // wave-wide min for uniform early break
    #pragma unroll
    for (int off = 32; off > 0; off >>= 1)
        um = fminf(um, __shfl_xor(um, off));
    const float umin = um;
    const int lb = (tid & 63) & ~3;            // group base lane (fallback path)

    if (valid) {
        float acc0=0.f, acc1=0.f, acc2=0.f, acc3=0.f;
        const float* s4k = scan4 + (size_t)(b * N + k0) * NGP;
        float g0c = s4k[q];                    // padded row: [0]=0
        float g1c = s4k[q + 1];

        for (int k = k0; k < kend; ++k) {
            const int   kk = k - k0;
            const float kc = kcs[kk];
            if (kc * umin >= NYQF) break;      // wave-uniform; kc monotone in k
            const float G0 = g0c, G1 = g1c;
            if (k + 1 < kend) {                // prefetch next k row
                const float* nx = s4k + NGP;
                g0c = nx[q];
                g1c = nx[q + 1];
                s4k = nx;
            }

            // lane-local increments (bit-exact vs ref elementwise ops)
            float x0 = div48000(TWO_PI_F * (kc * u0));
            float x1 = div48000(TWO_PI_F * (kc * u1));
            float x2 = div48000(TWO_PI_F * (kc * u2));
            float x3 = div48000(TWO_PI_F * (kc * u3));
            float L1p = x0 + x1, L1q = x2 + x3;
            float L2  = L1p + L1q;

            // group L2 partials (FP add commutative bitwise -> exact assoc)
            float s0 = grp4_bcast<0>(L2, lb);
            float s1 = grp4_bcast<1>(L2, lb);
            float s2 = grp4_bcast<2>(L2, lb);
            float t01 = s0 + s1;
            float b1v = G0 + s0;               // s20
            float b2v = G0 + t01;              // s3v  (g0 + (L2a+L2b))
            float b3v = b2v + s2;              // s22
            float base = (c == 0) ? G0  : (c == 1) ? b1v : (c == 2) ? b2v : b3v;
            float bn   = (c == 0) ? b1v : (c == 1) ? b2v : (c == 2) ? b3v : G1;

            float ph0 = base + x0;
            float ph1 = base + L1p;
            float ph2 = ph1 + x2;
            float ph3 = bn;

            {   float t1 = kc * u0;            // same RN product as ref mask
                if (t1 < NYQF) { float sv = sin_phase(ph0);
                    float2 a = amps[a0o + kk];
                    acc0 = __builtin_fmaf(__builtin_fmaf(w0, a.y, a.x), sv, acc0); } }
            {   float t1 = kc * u1;
                if (t1 < NYQF) { float sv = sin_phase(ph1);
                    float2 a = amps[a1o + kk];
                    acc1 = __builtin_fmaf(__builtin_fmaf(w1, a.y, a.x), sv, acc1); } }
            {   float t1 = kc * u2;
                if (t1 < NYQF) { float sv = sin_phase(ph2);
                    float2 a = amps[a2o + kk];
                    acc2 = __builtin_fmaf(__builtin_fmaf(w2, a.y, a.x), sv, acc2); } }
            {   float t1 = kc * u3;
                if (t1 < NYQF) { float sv = sin_phase(ph3);
                    float2 a = amps[a3o + kk];
                    acc3 = __builtin_fmaf(__builtin_fmaf(w3, a.y, a.x), sv, acc3); } }
        }

        const float Nf = (float)N;
        float* ob = out + (size_t)b * n + (size_t)q * 16 + c * 4;
        atomicAdd(&ob[0], acc0 / Nf);
        atomicAdd(&ob[1], acc1 / Nf);
        atomicAdd(&ob[2], acc2 / Nf);
        atomicAdd(&ob[3], acc3 / Nf);
    }
}

// ---- Fallback: round-5 proven kernel (atomics, 96 KB LDS) ------------------
__global__ void __launch_bounds__(256) k_scan_synth(
        const float* __restrict__ harm, const float* __restrict__ f0up,
        const float* __restrict__ inh,  float* __restrict__ out,
        int B, int T, int N, int n, float pf) {
    extern __shared__ float lv[];
    const int k   = blockIdx.x;
    const int b   = blockIdx.y;
    const int tid = threadIdx.x;
    const float kc = kcval(k, inh[b]);
    const float* fb = f0up + (size_t)b * n;

    auto inc = [&](int j) -> float {
        float u    = fb[j];
        float inst = kc * u;
        float tt   = TWO_PI_F * inst;
        return tt / SRF;
    };

    const int len1 = n >> 1;
    {
        const float4* f4 = (const float4*)fb;
        for (int i = tid; i < (n >> 2); i += 256) {
            float4 u = f4[i];
            float a0 = (TWO_PI_F * (kc * u.x)) / SRF;
            float a1 = (TWO_PI_F * (kc * u.y)) / SRF;
            float a2 = (TWO_PI_F * (kc * u.z)) / SRF;
            float a3 = (TWO_PI_F * (kc * u.w)) / SRF;
            lv[i] = (a0 + a1) + (a2 + a3);
        }
    }
    __syncthreads();
    int offp = 0, lenp = n >> 2, P = 2;
    for (int l = 3; ; ++l) {
        int lenc = lenp >> 1;
        int offc = offp + lenp;
        for (int i = tid; i < lenc; i += 256)
            lv[offc + i] = lv[offp + 2*i] + lv[offp + 2*i + 1];
        __syncthreads();
        P = l;
        if (lenc == 1) break;
        offp = offc; lenp = lenc;
    }
    for (int l = P - 1; l >= 2; --l) {
        int lenl = n >> l;
        int offl = 0;
        for (int m = 2; m < l; ++m) offl += (n >> m);
        float*       arr = lv + offl;
        const float* hi  = lv + offl + lenl;
        int lenh = n >> (l + 1);
        for (int i = tid; i < lenh; i += 256) {
            float v = hi[i];
            int e = 2*i + 2;
            if (e < lenl) arr[e] = v + arr[e];
            arr[2*i + 1] = v;
        }
        __syncthreads();
    }
    const float* scan2 = lv;

    const float  tmaxf = (float)(T - 1);
    const float  invN  = 1.0f / (float)N;
    const float* hb    = harm + (size_t)b * T * N + k;
    float*       ob    = out + (size_t)b * n;

    auto emit = [&](int j, float ph) {
        float u    = fb[j];
        float inst = kc * u;
        if (!(inst < NYQF)) return;
        double pr = (double)ph * INV_2PI_D;
        double fr = pr - rint(pr);
        float  sv = hsin_rev((float)fr);
        float pos = ((float)j + 0.5f);
        pos = pos * pf; pos = pos - 0.5f;
        pos = fmaxf(pos, 0.0f); pos = fminf(pos, tmaxf);
        int   i0 = (int)pos;
        int   i1 = min(i0 + 1, T - 1);
        float w  = pos - (float)i0;
        float a  = hb[(size_t)i0 * N] * (1.0f - w) + hb[(size_t)i1 * N] * w;
        atomicAdd(&ob[j], (a * sv) * invN);
    };

    if (tid == 0) emit(0, inc(0));
    for (int tt = tid; tt < len1; tt += 256) {
        float s1;
        if (tt == 0)      s1 = inc(0) + inc(1);
        else if (tt & 1)  s1 = scan2[(tt - 1) >> 1];
        else              s1 = scan2[(tt >> 1) - 1] + (inc(2*tt) + inc(2*tt + 1));
        emit(2*tt + 1, s1);
        int je = 2*tt + 2;
        if (je < n) emit(je, s1 + inc(je));
    }
}

extern "C" void kernel_launch(void* const* d_in, const int* in_sizes, int n_in,
                              void* d_out, int out_size, void* d_ws, size_t ws_size,
                              hipStream_t stream) {
    const int B = in_sizes[2];                 // 16
    const int T = in_sizes[1] / B;             // 250
    const int N = in_sizes[0] / (B * T);       // 100
    const int n = out_size / B;                // 48000
    const float pf = (float)((double)T / (double)n);

    const float* harm = (const float*)d_in[0];
    const float* f0   = (const float*)d_in[1];
    const float* inh  = (const float*)d_in[2];
    float* out  = (float*)d_out;
    float* f0up = (float*)d_ws;                // B*n floats = 3.07 MB

    const int KZ  = 2;
    const int kpg = (N + KZ - 1) / KZ;         // 50
    const int NG  = n / 16;                    // 3000
    const size_t needFast = (size_t)B * n * 4 + (size_t)B * N * (NG + 1) * 4;
    const bool fast = (ws_size >= needFast) && (n % 16 == 0) && (kpg <= 64);

    k_f0up<<<dim3((n + 255) / 256, B), 256, 0, stream>>>(f0, f0up, out, T, n, pf);

    if (fast) {
        float* scan4 = (float*)((char*)d_ws + (size_t)B * n * 4);
        k_scan4<<<dim3(N, B), SCAN_TPB, 0, stream>>>(f0up, inh, scan4, N, n);
        const int tiles = (NG * 4 + 255) / 256;            // 47
        k_synth4<<<dim3(tiles, B, KZ), 256, 0, stream>>>(
            harm, f0up, inh, scan4, out, B, T, N, n, pf, kpg);
    } else {
        const size_t lds_bytes = (size_t)(n / 2) * sizeof(float);  // 96 KB
        k_scan_synth<<<dim3(N, B), 256, lds_bytes, stream>>>(
            harm, f0up, inh, out, B, T, N, n, pf);
    }
}